// Round 1
// baseline (3935.956 us; speedup 1.0000x reference)
//
#include <hip/hip_runtime.h>

#define S 4096
#define BATCH 2
#define D 768
#define NH 12
#define DH 64
#define NROWS (BATCH * S)

// ---------------------------------------------------------------------------
// QKV projection: x[N,768] @ W[768,768] for W in {Wq,Wk,Wv}; output scattered
// to [B, NH, S, DH] so the attention kernel reads contiguous rows per head.
// grid (NROWS/64, NH, 3), block 256. 64x64 tile, 4x4 microtile per thread.
// ---------------------------------------------------------------------------
__global__ __launch_bounds__(256) void qkv_gemm(
    const float* __restrict__ x,
    const float* __restrict__ Wq, const float* __restrict__ Wk,
    const float* __restrict__ Wv,
    float* __restrict__ qb, float* __restrict__ kb, float* __restrict__ vb)
{
    __shared__ float As[64][17];   // +1 pad breaks 4-way bank aliasing
    __shared__ float Bs[16][64];

    const int t = threadIdx.x;
    const int tx = t & 15, ty = t >> 4;
    const int row0 = blockIdx.x * 64;
    const int h = blockIdx.y;          // one head's 64 columns per tile
    const int col0 = h * 64;
    const float* W = (blockIdx.z == 0) ? Wq : (blockIdx.z == 1 ? Wk : Wv);
    float* outp = (blockIdx.z == 0) ? qb : (blockIdx.z == 1 ? kb : vb);

    float acc[4][4] = {};
    const int arow = t >> 2, acol = (t & 3) * 4;
    const int brow = t >> 4, bcol = (t & 15) * 4;

    for (int k0 = 0; k0 < D; k0 += 16) {
        float4 a4 = *(const float4*)(x + (size_t)(row0 + arow) * D + k0 + acol);
        As[arow][acol + 0] = a4.x;
        As[arow][acol + 1] = a4.y;
        As[arow][acol + 2] = a4.z;
        As[arow][acol + 3] = a4.w;
        *(float4*)&Bs[brow][bcol] =
            *(const float4*)(W + (size_t)(k0 + brow) * D + col0 + bcol);
        __syncthreads();
#pragma unroll
        for (int kk = 0; kk < 16; ++kk) {
            float a[4], bb[4];
#pragma unroll
            for (int i = 0; i < 4; ++i) a[i] = As[ty * 4 + i][kk];
#pragma unroll
            for (int j = 0; j < 4; ++j) bb[j] = Bs[kk][tx * 4 + j];
#pragma unroll
            for (int i = 0; i < 4; ++i)
#pragma unroll
                for (int j = 0; j < 4; ++j) acc[i][j] += a[i] * bb[j];
        }
        __syncthreads();
    }
#pragma unroll
    for (int i = 0; i < 4; ++i) {
        int n = row0 + ty * 4 + i;
        int b = n >> 12;            // n / 4096
        int s = n & 4095;
        size_t base = (((size_t)b * NH + h) * S + s) * DH + tx * 4;
        float4 o4 = make_float4(acc[i][0], acc[i][1], acc[i][2], acc[i][3]);
        *(float4*)(outp + base) = o4;
    }
}

// ---------------------------------------------------------------------------
// Flash-style causal attention, fp32. One block per (q-tile of 64, head, b).
// 256 threads: thread t owns query row t>>2 and 16-wide col/d group t&3.
// LDS tiles padded to stride 68 (16B-aligned rows, conflict-light).
// grid (S/64, NH, BATCH), block 256.
// ---------------------------------------------------------------------------
__global__ __launch_bounds__(256) void attn_kernel(
    const float* __restrict__ qg, const float* __restrict__ kg,
    const float* __restrict__ vg, float* __restrict__ ctx)
{
    __shared__ float Qs[64][68];
    __shared__ float Ks[64][68];
    __shared__ float Vs[64][68];
    __shared__ float Ps[64][68];
    __shared__ float redm[64][4];
    __shared__ float redl[64][4];
    __shared__ float mrow[64];
    __shared__ float lrow[64];

    const float INF = __builtin_inff();
    const int t = threadIdx.x;
    const int qt = blockIdx.x, h = blockIdx.y, b = blockIdx.z;
    const size_t hbase = ((size_t)b * NH + h) * (size_t)S * DH;
    const float* qp = qg + hbase;
    const float* kp = kg + hbase;
    const float* vp = vg + hbase;

    const int lr = t >> 2;            // load row 0..63
    const int lc = (t & 3) * 16;      // load col group (16 floats)
    const int qrow = t >> 2;
    const int grp = t & 3;
    const int qglob = qt * 64 + qrow;

    // Load Q tile, fold in 1/sqrt(DH) = 0.125
#pragma unroll
    for (int i = 0; i < 4; ++i) {
        float4 a = *(const float4*)(qp + (size_t)(qt * 64 + lr) * DH + lc + i * 4);
        a.x *= 0.125f; a.y *= 0.125f; a.z *= 0.125f; a.w *= 0.125f;
        *(float4*)&Qs[lr][lc + i * 4] = a;
    }
    if (t < 64) { mrow[t] = -INF; lrow[t] = 0.f; }

    float4 o4[4];
#pragma unroll
    for (int i = 0; i < 4; ++i) o4[i] = make_float4(0.f, 0.f, 0.f, 0.f);

    for (int j = 0; j <= qt; ++j) {
        __syncthreads();   // prev PV reads done before overwriting K/V
#pragma unroll
        for (int i = 0; i < 4; ++i) {
            *(float4*)&Ks[lr][lc + i * 4] =
                *(const float4*)(kp + (size_t)(j * 64 + lr) * DH + lc + i * 4);
            *(float4*)&Vs[lr][lc + i * 4] =
                *(const float4*)(vp + (size_t)(j * 64 + lr) * DH + lc + i * 4);
        }
        __syncthreads();

        // scores: 16 columns per thread, dot over 64 via float4
        float scv[16];
#pragma unroll
        for (int cc = 0; cc < 16; ++cc) scv[cc] = 0.f;
#pragma unroll
        for (int k4 = 0; k4 < 16; ++k4) {
            float4 qv = *(const float4*)&Qs[qrow][k4 * 4];
#pragma unroll
            for (int cc = 0; cc < 16; ++cc) {
                float4 kv = *(const float4*)&Ks[grp * 16 + cc][k4 * 4];
                scv[cc] += qv.x * kv.x + qv.y * kv.y + qv.z * kv.z + qv.w * kv.w;
            }
        }
        const bool diag = (j == qt);
        float tmax = -INF;
#pragma unroll
        for (int cc = 0; cc < 16; ++cc) {
            int kglob = j * 64 + grp * 16 + cc;
            if (diag && kglob > qglob) scv[cc] = -INF;
            tmax = fmaxf(tmax, scv[cc]);
        }
        redm[qrow][grp] = tmax;
        __syncthreads();

        float m_old = mrow[qrow];
        float m_new = fmaxf(fmaxf(redm[qrow][0], redm[qrow][1]),
                            fmaxf(redm[qrow][2], redm[qrow][3]));
        m_new = fmaxf(m_old, m_new);
        float alpha = __expf(m_old - m_new);   // exp(-inf)=0 on first tile

        float psum = 0.f;
#pragma unroll
        for (int c4 = 0; c4 < 4; ++c4) {
            float4 p4;
            p4.x = __expf(scv[c4 * 4 + 0] - m_new);
            p4.y = __expf(scv[c4 * 4 + 1] - m_new);
            p4.z = __expf(scv[c4 * 4 + 2] - m_new);
            p4.w = __expf(scv[c4 * 4 + 3] - m_new);
            psum += p4.x + p4.y + p4.z + p4.w;
            *(float4*)&Ps[qrow][grp * 16 + c4 * 4] = p4;
        }
        redl[qrow][grp] = psum;
        __syncthreads();   // Ps + redl visible; old mrow/lrow reads done

        if (grp == 0) {
            float ls = redl[qrow][0] + redl[qrow][1] + redl[qrow][2] + redl[qrow][3];
            mrow[qrow] = m_new;
            lrow[qrow] = lrow[qrow] * alpha + ls;
        }

        // O = O*alpha + P·V (16 d's per thread)
#pragma unroll
        for (int d4 = 0; d4 < 4; ++d4) {
            o4[d4].x *= alpha; o4[d4].y *= alpha;
            o4[d4].z *= alpha; o4[d4].w *= alpha;
        }
#pragma unroll
        for (int kk = 0; kk < 64; ++kk) {
            float p = Ps[qrow][kk];
#pragma unroll
            for (int d4 = 0; d4 < 4; ++d4) {
                float4 vv = *(const float4*)&Vs[kk][grp * 16 + d4 * 4];
                o4[d4].x += p * vv.x; o4[d4].y += p * vv.y;
                o4[d4].z += p * vv.z; o4[d4].w += p * vv.w;
            }
        }
    }
    __syncthreads();
    float inv_l = 1.f / lrow[qrow];
    int n = b * S + qt * 64 + qrow;
    size_t obase = (size_t)n * D + (size_t)h * DH + grp * 16;
#pragma unroll
    for (int d4 = 0; d4 < 4; ++d4) {
        float4 o = o4[d4];
        o.x *= inv_l; o.y *= inv_l; o.z *= inv_l; o.w *= inv_l;
        *(float4*)(ctx + obase + d4 * 4) = o;
    }
}

// ---------------------------------------------------------------------------
// Output projection: ctx[N,768] @ Wo[768,768] + bo. grid (NROWS/64, D/64).
// ---------------------------------------------------------------------------
__global__ __launch_bounds__(256) void out_proj(
    const float* __restrict__ ctx, const float* __restrict__ Wo,
    const float* __restrict__ bo, float* __restrict__ out)
{
    __shared__ float As[64][17];
    __shared__ float Bs[16][64];

    const int t = threadIdx.x;
    const int tx = t & 15, ty = t >> 4;
    const int row0 = blockIdx.x * 64;
    const int col0 = blockIdx.y * 64;

    float acc[4][4] = {};
    const int arow = t >> 2, acol = (t & 3) * 4;
    const int brow = t >> 4, bcol = (t & 15) * 4;

    for (int k0 = 0; k0 < D; k0 += 16) {
        float4 a4 = *(const float4*)(ctx + (size_t)(row0 + arow) * D + k0 + acol);
        As[arow][acol + 0] = a4.x;
        As[arow][acol + 1] = a4.y;
        As[arow][acol + 2] = a4.z;
        As[arow][acol + 3] = a4.w;
        *(float4*)&Bs[brow][bcol] =
            *(const float4*)(Wo + (size_t)(k0 + brow) * D + col0 + bcol);
        __syncthreads();
#pragma unroll
        for (int kk = 0; kk < 16; ++kk) {
            float a[4], bb[4];
#pragma unroll
            for (int i = 0; i < 4; ++i) a[i] = As[ty * 4 + i][kk];
#pragma unroll
            for (int j = 0; j < 4; ++j) bb[j] = Bs[kk][tx * 4 + j];
#pragma unroll
            for (int i = 0; i < 4; ++i)
#pragma unroll
                for (int j = 0; j < 4; ++j) acc[i][j] += a[i] * bb[j];
        }
        __syncthreads();
    }
    float4 bv = *(const float4*)(bo + col0 + tx * 4);
#pragma unroll
    for (int i = 0; i < 4; ++i) {
        int n = row0 + ty * 4 + i;
        float4 o = make_float4(acc[i][0] + bv.x, acc[i][1] + bv.y,
                               acc[i][2] + bv.z, acc[i][3] + bv.w);
        *(float4*)(out + (size_t)n * D + col0 + tx * 4) = o;
    }
}

extern "C" void kernel_launch(void* const* d_in, const int* in_sizes, int n_in,
                              void* d_out, int out_size, void* d_ws, size_t ws_size,
                              hipStream_t stream)
{
    const float* x  = (const float*)d_in[0];
    const float* Wq = (const float*)d_in[1];
    const float* Wk = (const float*)d_in[2];
    const float* Wv = (const float*)d_in[3];
    const float* Wo = (const float*)d_in[4];
    const float* bo = (const float*)d_in[5];
    float* out = (float*)d_out;

    const size_t elems = (size_t)NROWS * D;   // 6,291,456 floats = 25.2 MB
    float* q   = (float*)d_ws;
    float* k   = q + elems;
    float* v   = k + elems;
    float* ctx = v + elems;                   // total 100.7 MB of workspace

    dim3 g1(NROWS / 64, NH, 3);
    qkv_gemm<<<g1, 256, 0, stream>>>(x, Wq, Wk, Wv, q, k, v);

    dim3 g2(S / 64, NH, BATCH);
    attn_kernel<<<g2, 256, 0, stream>>>(q, k, v, ctx);

    dim3 g3(NROWS / 64, D / 64);
    out_proj<<<g3, 256, 0, stream>>>(ctx, Wo, bo, out);
}

// Round 2
// 1046.962 us; speedup vs baseline: 3.7594x; 3.7594x over previous
//
#include <hip/hip_runtime.h>

#define S 4096
#define BATCH 2
#define D 768
#define NH 12
#define DH 64
#define NROWS (BATCH * S)

typedef __attribute__((ext_vector_type(8))) short bf16x8;   // 8 bf16 (4 VGPRs)
typedef __attribute__((ext_vector_type(4))) float f32x4;

__device__ __forceinline__ unsigned short f2bf(float f) {
    unsigned u = __builtin_bit_cast(unsigned, f);
    u += 0x7fff + ((u >> 16) & 1);          // round-to-nearest-even
    return (unsigned short)(u >> 16);
}

// ---------------------------------------------------------------------------
// QKV projection: x[N,768] @ W[768,768]; fp32 math, bf16 outputs.
// Q: [b,h,s,dh] bf16, scaled by 0.125 (1/sqrt(64)) at write time.
// K: [b,h,s,dh] bf16.
// V: written TRANSPOSED as [b,h,dh,s] bf16 so attention PV B-frags are
//    contiguous.
// grid (NROWS/64, NH, 3), block 256.
// ---------------------------------------------------------------------------
__global__ __launch_bounds__(256) void qkv_gemm(
    const float* __restrict__ x,
    const float* __restrict__ Wq, const float* __restrict__ Wk,
    const float* __restrict__ Wv,
    unsigned short* __restrict__ qb, unsigned short* __restrict__ kb,
    unsigned short* __restrict__ vtb)
{
    __shared__ float As[64][17];
    __shared__ float Bs[16][64];

    const int t = threadIdx.x;
    const int tx = t & 15, ty = t >> 4;
    const int row0 = blockIdx.x * 64;
    const int h = blockIdx.y;
    const int col0 = h * 64;
    const int z = blockIdx.z;
    const float* W = (z == 0) ? Wq : (z == 1 ? Wk : Wv);

    float acc[4][4] = {};
    const int arow = t >> 2, acol = (t & 3) * 4;
    const int brow = t >> 4, bcol = (t & 15) * 4;

    for (int k0 = 0; k0 < D; k0 += 16) {
        float4 a4 = *(const float4*)(x + (size_t)(row0 + arow) * D + k0 + acol);
        As[arow][acol + 0] = a4.x;
        As[arow][acol + 1] = a4.y;
        As[arow][acol + 2] = a4.z;
        As[arow][acol + 3] = a4.w;
        *(float4*)&Bs[brow][bcol] =
            *(const float4*)(W + (size_t)(k0 + brow) * D + col0 + bcol);
        __syncthreads();
#pragma unroll
        for (int kk = 0; kk < 16; ++kk) {
            float a[4], bb[4];
#pragma unroll
            for (int i = 0; i < 4; ++i) a[i] = As[ty * 4 + i][kk];
#pragma unroll
            for (int j = 0; j < 4; ++j) bb[j] = Bs[kk][tx * 4 + j];
#pragma unroll
            for (int i = 0; i < 4; ++i)
#pragma unroll
                for (int j = 0; j < 4; ++j) acc[i][j] += a[i] * bb[j];
        }
        __syncthreads();
    }

    if (z == 2) {
        // V transposed: vtb[((b*NH+h)*DH + dh)*S + s]; 4 consecutive s pack.
        int n = row0 + ty * 4;
        int b = n >> 12, s = n & 4095;
#pragma unroll
        for (int j = 0; j < 4; ++j) {
            ushort4 p;
            p.x = f2bf(acc[0][j]); p.y = f2bf(acc[1][j]);
            p.z = f2bf(acc[2][j]); p.w = f2bf(acc[3][j]);
            int dh = tx * 4 + j;
            size_t base = (((size_t)b * NH + h) * DH + dh) * (size_t)S + s;
            *(ushort4*)(vtb + base) = p;
        }
    } else {
        unsigned short* outp = (z == 0) ? qb : kb;
        const float scale = (z == 0) ? 0.125f : 1.0f;
#pragma unroll
        for (int i = 0; i < 4; ++i) {
            int n = row0 + ty * 4 + i;
            int b = n >> 12, s = n & 4095;
            ushort4 p;
            p.x = f2bf(acc[i][0] * scale); p.y = f2bf(acc[i][1] * scale);
            p.z = f2bf(acc[i][2] * scale); p.w = f2bf(acc[i][3] * scale);
            size_t base = (((size_t)b * NH + h) * (size_t)S + s) * DH + tx * 4;
            *(ushort4*)(outp + base) = p;
        }
    }
}

// ---------------------------------------------------------------------------
// Flash attention, bf16 MFMA (16x16x32). Block = 4 waves, 64 Q rows per
// (b, h, q-tile). Wave w owns Q rows w*16..w*16+15.
//  QK^T: A[m=qrow][k=dh] from Qs rows, B[k=dh][n=key] from Ks rows.
//  PV:   A[m=qrow][k=key] from per-wave Ps, B[k=key][n=dh] from Vs (=V^T).
// C/D layout: col = lane&15, row = (lane>>4)*4 + reg.
// LDS rows padded to 72 bf16 (144 B): bank advance 4/row -> free 2-way only.
// grid (S/64, NH, BATCH), block 256.
// ---------------------------------------------------------------------------
__global__ __launch_bounds__(256) void attn_mfma(
    const unsigned short* __restrict__ qg,
    const unsigned short* __restrict__ kg,
    const unsigned short* __restrict__ vtg,
    float* __restrict__ ctx)
{
    __shared__ unsigned short Qs[64][72];
    __shared__ unsigned short Ks[64][72];
    __shared__ unsigned short Vs[64][72];      // V^T tile: [dh][key]
    __shared__ unsigned short Ps[4][16][72];   // per-wave P: [qrow16][key]

    const float INF = __builtin_inff();
    const int t = threadIdx.x;
    const int w = t >> 6;
    const int lane = t & 63;
    const int l16 = lane & 15;
    const int quad = lane >> 4;
    const int qt = blockIdx.x, h = blockIdx.y, b = blockIdx.z;
    const size_t hbase = ((size_t)b * NH + h) * (size_t)S * DH;

    // --- stage Q tile (32 B per thread) ---
    {
        int r = t >> 2, c = (t & 3) * 16;
        const unsigned short* src = qg + hbase + (size_t)(qt * 64 + r) * DH + c;
        *(uint4*)&Qs[r][c]     = *(const uint4*)src;
        *(uint4*)&Qs[r][c + 8] = *(const uint4*)(src + 8);
    }
    __syncthreads();

    // Q A-fragments, reused across all K tiles: a_q[kk] covers dh kk*32+quad*8..+7
    bf16x8 a_q[2];
#pragma unroll
    for (int kk = 0; kk < 2; ++kk)
        a_q[kk] = *(const bf16x8*)&Qs[w * 16 + l16][kk * 32 + quad * 8];

    f32x4 acc_o[4] = {};                 // O: [dhsub] C-frags
    float m_prev[4], lsum[4];
#pragma unroll
    for (int r = 0; r < 4; ++r) { m_prev[r] = -INF; lsum[r] = 0.f; }

    for (int j = 0; j <= qt; ++j) {
        __syncthreads();                 // prior reads of Ks/Vs complete
        {
            int r = t >> 2, c = (t & 3) * 16;
            const unsigned short* ks = kg + hbase + (size_t)(j * 64 + r) * DH + c;
            *(uint4*)&Ks[r][c]     = *(const uint4*)ks;
            *(uint4*)&Ks[r][c + 8] = *(const uint4*)(ks + 8);
            const unsigned short* vs = vtg + hbase + (size_t)r * S + j * 64 + c;
            *(uint4*)&Vs[r][c]     = *(const uint4*)vs;
            *(uint4*)&Vs[r][c + 8] = *(const uint4*)(vs + 8);
        }
        __syncthreads();

        // --- S = Q K^T : 4 key-subtiles x 2 k-steps ---
        f32x4 acc_s[4] = {};
#pragma unroll
        for (int kk = 0; kk < 2; ++kk) {
#pragma unroll
            for (int ns = 0; ns < 4; ++ns) {
                bf16x8 bk = *(const bf16x8*)&Ks[ns * 16 + l16][kk * 32 + quad * 8];
                acc_s[ns] = __builtin_amdgcn_mfma_f32_16x16x32_bf16(
                    a_q[kk], bk, acc_s[ns], 0, 0, 0);
            }
        }

        // --- online softmax (per lane: rows quad*4+reg) ---
        const bool diag = (j == qt);
        float pv[4][4];                  // [nsub][reg]
#pragma unroll
        for (int reg = 0; reg < 4; ++reg) {
            int rowg = qt * 64 + w * 16 + quad * 4 + reg;
            float mx = -INF;
#pragma unroll
            for (int ns = 0; ns < 4; ++ns) {
                float s = acc_s[ns][reg];
                if (diag && (j * 64 + ns * 16 + l16) > rowg) s = -INF;
                acc_s[ns][reg] = s;
                mx = fmaxf(mx, s);
            }
            mx = fmaxf(mx, __shfl_xor(mx, 1));
            mx = fmaxf(mx, __shfl_xor(mx, 2));
            mx = fmaxf(mx, __shfl_xor(mx, 4));
            mx = fmaxf(mx, __shfl_xor(mx, 8));
            float mn = fmaxf(m_prev[reg], mx);
            float al = __expf(m_prev[reg] - mn);   // first tile: exp(-inf)=0
            m_prev[reg] = mn;
            float ps = 0.f;
#pragma unroll
            for (int ns = 0; ns < 4; ++ns) {
                float p = __expf(acc_s[ns][reg] - mn);
                pv[ns][reg] = p;
                ps += p;
            }
            ps += __shfl_xor(ps, 1);
            ps += __shfl_xor(ps, 2);
            ps += __shfl_xor(ps, 4);
            ps += __shfl_xor(ps, 8);
            lsum[reg] = lsum[reg] * al + ps;
#pragma unroll
            for (int d = 0; d < 4; ++d) acc_o[d][reg] *= al;
        }

        // --- P -> per-wave LDS (C-layout -> A-layout round trip) ---
#pragma unroll
        for (int ns = 0; ns < 4; ++ns)
#pragma unroll
            for (int reg = 0; reg < 4; ++reg)
                Ps[w][quad * 4 + reg][ns * 16 + l16] = f2bf(pv[ns][reg]);

        // --- O += P V : A from Ps, B from Vs ---
#pragma unroll
        for (int kk = 0; kk < 2; ++kk) {
            bf16x8 ap = *(const bf16x8*)&Ps[w][l16][kk * 32 + quad * 8];
#pragma unroll
            for (int d = 0; d < 4; ++d) {
                bf16x8 bv = *(const bf16x8*)&Vs[d * 16 + l16][kk * 32 + quad * 8];
                acc_o[d] = __builtin_amdgcn_mfma_f32_16x16x32_bf16(
                    ap, bv, acc_o[d], 0, 0, 0);
            }
        }
    }

    // --- epilogue: O /= l, write ctx [b, s, h*64+dh] fp32 ---
#pragma unroll
    for (int reg = 0; reg < 4; ++reg) {
        float inv = 1.f / lsum[reg];
        int n = b * S + qt * 64 + w * 16 + quad * 4 + reg;
        size_t base = (size_t)n * D + h * 64;
#pragma unroll
        for (int d = 0; d < 4; ++d)
            ctx[base + d * 16 + l16] = acc_o[d][reg] * inv;
    }
}

// ---------------------------------------------------------------------------
// Output projection: ctx[N,768] @ Wo[768,768] + bo. grid (NROWS/64, D/64).
// ---------------------------------------------------------------------------
__global__ __launch_bounds__(256) void out_proj(
    const float* __restrict__ ctx, const float* __restrict__ Wo,
    const float* __restrict__ bo, float* __restrict__ out)
{
    __shared__ float As[64][17];
    __shared__ float Bs[16][64];

    const int t = threadIdx.x;
    const int tx = t & 15, ty = t >> 4;
    const int row0 = blockIdx.x * 64;
    const int col0 = blockIdx.y * 64;

    float acc[4][4] = {};
    const int arow = t >> 2, acol = (t & 3) * 4;
    const int brow = t >> 4, bcol = (t & 15) * 4;

    for (int k0 = 0; k0 < D; k0 += 16) {
        float4 a4 = *(const float4*)(ctx + (size_t)(row0 + arow) * D + k0 + acol);
        As[arow][acol + 0] = a4.x;
        As[arow][acol + 1] = a4.y;
        As[arow][acol + 2] = a4.z;
        As[arow][acol + 3] = a4.w;
        *(float4*)&Bs[brow][bcol] =
            *(const float4*)(Wo + (size_t)(k0 + brow) * D + col0 + bcol);
        __syncthreads();
#pragma unroll
        for (int kk = 0; kk < 16; ++kk) {
            float a[4], bb[4];
#pragma unroll
            for (int i = 0; i < 4; ++i) a[i] = As[ty * 4 + i][kk];
#pragma unroll
            for (int j = 0; j < 4; ++j) bb[j] = Bs[kk][tx * 4 + j];
#pragma unroll
            for (int i = 0; i < 4; ++i)
#pragma unroll
                for (int j = 0; j < 4; ++j) acc[i][j] += a[i] * bb[j];
        }
        __syncthreads();
    }
    float4 bv = *(const float4*)(bo + col0 + tx * 4);
#pragma unroll
    for (int i = 0; i < 4; ++i) {
        int n = row0 + ty * 4 + i;
        float4 o = make_float4(acc[i][0] + bv.x, acc[i][1] + bv.y,
                               acc[i][2] + bv.z, acc[i][3] + bv.w);
        *(float4*)(out + (size_t)n * D + col0 + tx * 4) = o;
    }
}

extern "C" void kernel_launch(void* const* d_in, const int* in_sizes, int n_in,
                              void* d_out, int out_size, void* d_ws, size_t ws_size,
                              hipStream_t stream)
{
    const float* x  = (const float*)d_in[0];
    const float* Wq = (const float*)d_in[1];
    const float* Wk = (const float*)d_in[2];
    const float* Wv = (const float*)d_in[3];
    const float* Wo = (const float*)d_in[4];
    const float* bo = (const float*)d_in[5];
    float* out = (float*)d_out;

    const size_t elems = (size_t)NROWS * D;     // 6,291,456
    unsigned short* q  = (unsigned short*)d_ws; // bf16, 12.6 MB each
    unsigned short* k  = q + elems;
    unsigned short* vt = k + elems;
    float* ctx = (float*)(vt + elems);          // fp32, 25.2 MB

    dim3 g1(NROWS / 64, NH, 3);
    qkv_gemm<<<g1, 256, 0, stream>>>(x, Wq, Wk, Wv, q, k, vt);

    dim3 g2(S / 64, NH, BATCH);
    attn_mfma<<<g2, 256, 0, stream>>>(q, k, vt, ctx);

    dim3 g3(NROWS / 64, D / 64);
    out_proj<<<g3, 256, 0, stream>>>(ctx, Wo, bo, out);
}

// Round 3
// 464.246 us; speedup vs baseline: 8.4782x; 2.2552x over previous
//
#include <hip/hip_runtime.h>

#define S 4096
#define BATCH 2
#define D 768
#define NH 12
#define DH 64
#define NROWS (BATCH * S)

typedef __attribute__((ext_vector_type(8))) short bf16x8;   // 8 bf16 (4 VGPRs)
typedef __attribute__((ext_vector_type(4))) float f32x4;

__device__ __forceinline__ unsigned short f2bf(float f) {
    unsigned u = __builtin_bit_cast(unsigned, f);
    u += 0x7fff + ((u >> 16) & 1);          // round-to-nearest-even
    return (unsigned short)(u >> 16);
}

// async global->LDS, 16B per lane; lptr must be wave-uniform
#define GLDS16(g, l)                                                   \
    __builtin_amdgcn_global_load_lds(                                  \
        (const __attribute__((address_space(1))) void*)(g),            \
        (__attribute__((address_space(3))) void*)(l), 16, 0, 0)

// ---------------------------------------------------------------------------
// x (fp32 [8192][768]) -> bf16. grid 6144 x 256.
// ---------------------------------------------------------------------------
__global__ __launch_bounds__(256) void cvt_x(const float* __restrict__ x,
                                             unsigned short* __restrict__ xb)
{
    int i = (blockIdx.x * 256 + threadIdx.x) * 4;
    float4 v = *(const float4*)(x + i);
    ushort4 o = make_ushort4(f2bf(v.x), f2bf(v.y), f2bf(v.z), f2bf(v.w));
    *(ushort4*)(xb + i) = o;
}

// ---------------------------------------------------------------------------
// W[k][n] fp32 -> wt[z][n][k] bf16 (transposed), z in {Wq,Wk,Wv,Wo}.
// grid (24, 24, 4) x 256; 32x32 LDS tile.
// ---------------------------------------------------------------------------
__global__ __launch_bounds__(256) void cvt_w(
    const float* __restrict__ Wq, const float* __restrict__ Wk,
    const float* __restrict__ Wv, const float* __restrict__ Wo,
    unsigned short* __restrict__ wt)
{
    __shared__ float tile[32][33];
    const int z = blockIdx.z;
    const float* W = (z == 0) ? Wq : (z == 1) ? Wk : (z == 2) ? Wv : Wo;
    const int k0 = blockIdx.x * 32, n0 = blockIdx.y * 32;
    const int t = threadIdx.x;
    const int r = t >> 3, c4 = (t & 7) * 4;

    float4 v = *(const float4*)(W + (size_t)(k0 + r) * D + n0 + c4);
    tile[r][c4 + 0] = v.x; tile[r][c4 + 1] = v.y;
    tile[r][c4 + 2] = v.z; tile[r][c4 + 3] = v.w;
    __syncthreads();
    ushort4 o = make_ushort4(f2bf(tile[c4 + 0][r]), f2bf(tile[c4 + 1][r]),
                             f2bf(tile[c4 + 2][r]), f2bf(tile[c4 + 3][r]));
    *(ushort4*)(wt + ((size_t)z * D + n0 + r) * D + k0 + c4) = o;
}

// ---------------------------------------------------------------------------
// QKV GEMM, bf16 MFMA. A = xb [8192][768], B = wt[z][n][k] (z = n0/768).
// 128x128 tile, BK=64, global_load_lds staging with XOR-8 swizzle.
// Block 256 = 4 waves in 2x2; each wave 64x64 (4x4 MFMA 16x16x32).
// Epilogue: z<2 -> Q(scaled)/K at [b,h,s,dh]; z==2 -> V^T at [b,h,dh,s].
// grid (64, 18).
// ---------------------------------------------------------------------------
__global__ __launch_bounds__(256) void gemm_qkv(
    const unsigned short* __restrict__ xb,
    const unsigned short* __restrict__ wt,
    unsigned short* __restrict__ qb, unsigned short* __restrict__ kb,
    unsigned short* __restrict__ vtb)
{
    __shared__ unsigned short As[128 * 64];
    __shared__ unsigned short Bs[128 * 64];

    const int t = threadIdx.x;
    const int lane = t & 63, w = t >> 6;
    const int l16 = lane & 15, quad = lane >> 4;
    const int wm = w & 1, wn = w >> 1;
    const int m0 = blockIdx.x * 128;
    const int n0g = blockIdx.y * 128;
    const int z = n0g / 768;
    const int c0 = n0g - z * 768;
    const unsigned short* Wz = wt + (size_t)z * D * D;

    f32x4 acc[4][4] = {};

    for (int k0 = 0; k0 < D; k0 += 64) {
#pragma unroll
        for (int i = 0; i < 4; ++i) {
            int g = i * 256 + w * 64 + lane;
            int row = g >> 3, cl = g & 7, cg = cl ^ (row & 7);
            GLDS16(xb + (size_t)(m0 + row) * D + k0 + cg * 8,
                   As + (size_t)(i * 256 + w * 64) * 8);
            GLDS16(Wz + (size_t)(c0 + row) * D + k0 + cg * 8,
                   Bs + (size_t)(i * 256 + w * 64) * 8);
        }
        __syncthreads();
#pragma unroll
        for (int kk = 0; kk < 2; ++kk) {
            bf16x8 af[4], bf_[4];
#pragma unroll
            for (int mt = 0; mt < 4; ++mt) {
                int r = wm * 64 + mt * 16 + l16;
                int c = kk * 4 + quad;
                af[mt] = *(const bf16x8*)&As[(r * 8 + (c ^ (r & 7))) * 8];
            }
#pragma unroll
            for (int nt = 0; nt < 4; ++nt) {
                int r = wn * 64 + nt * 16 + l16;
                int c = kk * 4 + quad;
                bf_[nt] = *(const bf16x8*)&Bs[(r * 8 + (c ^ (r & 7))) * 8];
            }
#pragma unroll
            for (int mt = 0; mt < 4; ++mt)
#pragma unroll
                for (int nt = 0; nt < 4; ++nt)
                    acc[mt][nt] = __builtin_amdgcn_mfma_f32_16x16x32_bf16(
                        af[mt], bf_[nt], acc[mt][nt], 0, 0, 0);
        }
        __syncthreads();
    }

    if (z < 2) {
        unsigned short* outp = (z == 0) ? qb : kb;
        const float scale = (z == 0) ? 0.125f : 1.0f;
#pragma unroll
        for (int mt = 0; mt < 4; ++mt) {
#pragma unroll
            for (int reg = 0; reg < 4; ++reg) {
                int m = wm * 64 + mt * 16 + quad * 4 + reg;
                int ng = m0 + m;
                int b = ng >> 12, s = ng & 4095;
#pragma unroll
                for (int nt = 0; nt < 4; ++nt) {
                    int n = c0 + wn * 64 + nt * 16 + l16;
                    int h = n >> 6, dh = n & 63;
                    outp[(((size_t)b * NH + h) * S + s) * DH + dh] =
                        f2bf(acc[mt][nt][reg] * scale);
                }
            }
        }
    } else {
#pragma unroll
        for (int mt = 0; mt < 4; ++mt) {
#pragma unroll
            for (int nt = 0; nt < 4; ++nt) {
                int m = wm * 64 + mt * 16 + quad * 4;
                int ng = m0 + m;
                int b = ng >> 12, s = ng & 4095;
                int n = c0 + wn * 64 + nt * 16 + l16;
                int h = n >> 6, dh = n & 63;
                ushort4 p = make_ushort4(
                    f2bf(acc[mt][nt][0]), f2bf(acc[mt][nt][1]),
                    f2bf(acc[mt][nt][2]), f2bf(acc[mt][nt][3]));
                *(ushort4*)(vtb + (((size_t)b * NH + h) * DH + dh) * S + s) = p;
            }
        }
    }
}

// ---------------------------------------------------------------------------
// Flash attention, bf16 MFMA (16x16x32). Unchanged from round 2 except the
// context output is now bf16 (feeds the MFMA out-projection).
// grid (S/64, NH, BATCH), block 256.
// ---------------------------------------------------------------------------
__global__ __launch_bounds__(256) void attn_mfma(
    const unsigned short* __restrict__ qg,
    const unsigned short* __restrict__ kg,
    const unsigned short* __restrict__ vtg,
    unsigned short* __restrict__ ctxb)
{
    __shared__ unsigned short Qs[64][72];
    __shared__ unsigned short Ks[64][72];
    __shared__ unsigned short Vs[64][72];      // V^T tile: [dh][key]
    __shared__ unsigned short Ps[4][16][72];   // per-wave P: [qrow16][key]

    const float INF = __builtin_inff();
    const int t = threadIdx.x;
    const int w = t >> 6;
    const int lane = t & 63;
    const int l16 = lane & 15;
    const int quad = lane >> 4;
    const int qt = blockIdx.x, h = blockIdx.y, b = blockIdx.z;
    const size_t hbase = ((size_t)b * NH + h) * (size_t)S * DH;

    {
        int r = t >> 2, c = (t & 3) * 16;
        const unsigned short* src = qg + hbase + (size_t)(qt * 64 + r) * DH + c;
        *(uint4*)&Qs[r][c]     = *(const uint4*)src;
        *(uint4*)&Qs[r][c + 8] = *(const uint4*)(src + 8);
    }
    __syncthreads();

    bf16x8 a_q[2];
#pragma unroll
    for (int kk = 0; kk < 2; ++kk)
        a_q[kk] = *(const bf16x8*)&Qs[w * 16 + l16][kk * 32 + quad * 8];

    f32x4 acc_o[4] = {};
    float m_prev[4], lsum[4];
#pragma unroll
    for (int r = 0; r < 4; ++r) { m_prev[r] = -INF; lsum[r] = 0.f; }

    for (int j = 0; j <= qt; ++j) {
        __syncthreads();
        {
            int r = t >> 2, c = (t & 3) * 16;
            const unsigned short* ks = kg + hbase + (size_t)(j * 64 + r) * DH + c;
            *(uint4*)&Ks[r][c]     = *(const uint4*)ks;
            *(uint4*)&Ks[r][c + 8] = *(const uint4*)(ks + 8);
            const unsigned short* vs = vtg + hbase + (size_t)r * S + j * 64 + c;
            *(uint4*)&Vs[r][c]     = *(const uint4*)vs;
            *(uint4*)&Vs[r][c + 8] = *(const uint4*)(vs + 8);
        }
        __syncthreads();

        f32x4 acc_s[4] = {};
#pragma unroll
        for (int kk = 0; kk < 2; ++kk) {
#pragma unroll
            for (int ns = 0; ns < 4; ++ns) {
                bf16x8 bk = *(const bf16x8*)&Ks[ns * 16 + l16][kk * 32 + quad * 8];
                acc_s[ns] = __builtin_amdgcn_mfma_f32_16x16x32_bf16(
                    a_q[kk], bk, acc_s[ns], 0, 0, 0);
            }
        }

        const bool diag = (j == qt);
        float pv[4][4];
#pragma unroll
        for (int reg = 0; reg < 4; ++reg) {
            int rowg = qt * 64 + w * 16 + quad * 4 + reg;
            float mx = -INF;
#pragma unroll
            for (int ns = 0; ns < 4; ++ns) {
                float s = acc_s[ns][reg];
                if (diag && (j * 64 + ns * 16 + l16) > rowg) s = -INF;
                acc_s[ns][reg] = s;
                mx = fmaxf(mx, s);
            }
            mx = fmaxf(mx, __shfl_xor(mx, 1));
            mx = fmaxf(mx, __shfl_xor(mx, 2));
            mx = fmaxf(mx, __shfl_xor(mx, 4));
            mx = fmaxf(mx, __shfl_xor(mx, 8));
            float mn = fmaxf(m_prev[reg], mx);
            float al = __expf(m_prev[reg] - mn);
            m_prev[reg] = mn;
            float ps = 0.f;
#pragma unroll
            for (int ns = 0; ns < 4; ++ns) {
                float p = __expf(acc_s[ns][reg] - mn);
                pv[ns][reg] = p;
                ps += p;
            }
            ps += __shfl_xor(ps, 1);
            ps += __shfl_xor(ps, 2);
            ps += __shfl_xor(ps, 4);
            ps += __shfl_xor(ps, 8);
            lsum[reg] = lsum[reg] * al + ps;
#pragma unroll
            for (int d = 0; d < 4; ++d) acc_o[d][reg] *= al;
        }

#pragma unroll
        for (int ns = 0; ns < 4; ++ns)
#pragma unroll
            for (int reg = 0; reg < 4; ++reg)
                Ps[w][quad * 4 + reg][ns * 16 + l16] = f2bf(pv[ns][reg]);

#pragma unroll
        for (int kk = 0; kk < 2; ++kk) {
            bf16x8 ap = *(const bf16x8*)&Ps[w][l16][kk * 32 + quad * 8];
#pragma unroll
            for (int d = 0; d < 4; ++d) {
                bf16x8 bv = *(const bf16x8*)&Vs[d * 16 + l16][kk * 32 + quad * 8];
                acc_o[d] = __builtin_amdgcn_mfma_f32_16x16x32_bf16(
                    ap, bv, acc_o[d], 0, 0, 0);
            }
        }
    }

#pragma unroll
    for (int reg = 0; reg < 4; ++reg) {
        float inv = 1.f / lsum[reg];
        int n = b * S + qt * 64 + w * 16 + quad * 4 + reg;
        size_t base = (size_t)n * D + h * 64;
#pragma unroll
        for (int d = 0; d < 4; ++d)
            ctxb[base + d * 16 + l16] = f2bf(acc_o[d][reg] * inv);
    }
}

// ---------------------------------------------------------------------------
// Output projection, bf16 MFMA. A = ctxb [8192][768], B = wt[3] (Wo^T),
// +bias, fp32 out. grid (64, 6).
// ---------------------------------------------------------------------------
__global__ __launch_bounds__(256) void gemm_out(
    const unsigned short* __restrict__ ctxb,
    const unsigned short* __restrict__ wt,
    const float* __restrict__ bo,
    float* __restrict__ out)
{
    __shared__ unsigned short As[128 * 64];
    __shared__ unsigned short Bs[128 * 64];

    const int t = threadIdx.x;
    const int lane = t & 63, w = t >> 6;
    const int l16 = lane & 15, quad = lane >> 4;
    const int wm = w & 1, wn = w >> 1;
    const int m0 = blockIdx.x * 128;
    const int n0 = blockIdx.y * 128;
    const unsigned short* Wz = wt + (size_t)3 * D * D;

    f32x4 acc[4][4] = {};

    for (int k0 = 0; k0 < D; k0 += 64) {
#pragma unroll
        for (int i = 0; i < 4; ++i) {
            int g = i * 256 + w * 64 + lane;
            int row = g >> 3, cl = g & 7, cg = cl ^ (row & 7);
            GLDS16(ctxb + (size_t)(m0 + row) * D + k0 + cg * 8,
                   As + (size_t)(i * 256 + w * 64) * 8);
            GLDS16(Wz + (size_t)(n0 + row) * D + k0 + cg * 8,
                   Bs + (size_t)(i * 256 + w * 64) * 8);
        }
        __syncthreads();
#pragma unroll
        for (int kk = 0; kk < 2; ++kk) {
            bf16x8 af[4], bf_[4];
#pragma unroll
            for (int mt = 0; mt < 4; ++mt) {
                int r = wm * 64 + mt * 16 + l16;
                int c = kk * 4 + quad;
                af[mt] = *(const bf16x8*)&As[(r * 8 + (c ^ (r & 7))) * 8];
            }
#pragma unroll
            for (int nt = 0; nt < 4; ++nt) {
                int r = wn * 64 + nt * 16 + l16;
                int c = kk * 4 + quad;
                bf_[nt] = *(const bf16x8*)&Bs[(r * 8 + (c ^ (r & 7))) * 8];
            }
#pragma unroll
            for (int mt = 0; mt < 4; ++mt)
#pragma unroll
                for (int nt = 0; nt < 4; ++nt)
                    acc[mt][nt] = __builtin_amdgcn_mfma_f32_16x16x32_bf16(
                        af[mt], bf_[nt], acc[mt][nt], 0, 0, 0);
        }
        __syncthreads();
    }

    float bv[4];
#pragma unroll
    for (int nt = 0; nt < 4; ++nt)
        bv[nt] = bo[n0 + wn * 64 + nt * 16 + l16];
#pragma unroll
    for (int mt = 0; mt < 4; ++mt)
#pragma unroll
        for (int reg = 0; reg < 4; ++reg) {
            int m = m0 + wm * 64 + mt * 16 + quad * 4 + reg;
#pragma unroll
            for (int nt = 0; nt < 4; ++nt)
                out[(size_t)m * D + n0 + wn * 64 + nt * 16 + l16] =
                    acc[mt][nt][reg] + bv[nt];
        }
}

extern "C" void kernel_launch(void* const* d_in, const int* in_sizes, int n_in,
                              void* d_out, int out_size, void* d_ws, size_t ws_size,
                              hipStream_t stream)
{
    const float* x  = (const float*)d_in[0];
    const float* Wq = (const float*)d_in[1];
    const float* Wk = (const float*)d_in[2];
    const float* Wv = (const float*)d_in[3];
    const float* Wo = (const float*)d_in[4];
    const float* bo = (const float*)d_in[5];
    float* out = (float*)d_out;

    const size_t elems = (size_t)NROWS * D;     // 6,291,456
    unsigned short* xb   = (unsigned short*)d_ws;
    unsigned short* wt   = xb + elems;          // 4 * 768 * 768
    unsigned short* q    = wt + (size_t)4 * D * D;
    unsigned short* k    = q + elems;
    unsigned short* vt   = k + elems;
    unsigned short* ctxb = vt + elems;          // ~68 MB total

    cvt_x<<<NROWS * D / 1024, 256, 0, stream>>>(x, xb);
    dim3 gw(D / 32, D / 32, 4);
    cvt_w<<<gw, 256, 0, stream>>>(Wq, Wk, Wv, Wo, wt);

    dim3 g1(NROWS / 128, (3 * D) / 128);
    gemm_qkv<<<g1, 256, 0, stream>>>(xb, wt, q, k, vt);

    dim3 g2(S / 64, NH, BATCH);
    attn_mfma<<<g2, 256, 0, stream>>>(q, k, vt, ctxb);

    dim3 g3(NROWS / 128, D / 128);
    gemm_out<<<g3, 256, 0, stream>>>(ctxb, wt, bo, out);
}